// Round 11
// baseline (176.226 us; speedup 1.0000x reference)
//
#include <hip/hip_runtime.h>
#include <hip/hip_bf16.h>
#include <hip/hip_cooperative_groups.h>

namespace cg = cooperative_groups;

typedef float f32x4 __attribute__((ext_vector_type(4)));
typedef __bf16 bf16x8 __attribute__((ext_vector_type(8)));
typedef unsigned short ushort8 __attribute__((ext_vector_type(8)));
typedef unsigned short u16x4 __attribute__((ext_vector_type(4)));

constexpr int kB = 2048;
constexpr int kF = 40;
constexpr int kD = 64;
constexpr int kP = 780;            // 40*39/2
constexpr int kFD = kF * kD;       // 2560

constexpr size_t W2_BYTES  = (size_t)kP * 512 * 16;   // 6.39 MB packed W
constexpr size_t WS_NEEDED = W2_BYTES;

__device__ __forceinline__ unsigned short f2bf_bits(float f) {
  unsigned u = __builtin_bit_cast(unsigned, f);
  u += 0x7FFFu + ((u >> 16) & 1u);
  return (unsigned short)(u >> 16);
}
__device__ __forceinline__ float bf2f(unsigned short u) {
  return __builtin_bit_cast(float, (unsigned)u << 16);
}

// pair loop over staged LDS tile (byte-identical logic to round-8's passing v4)
//   mfma(bfragW, afragX): afrag[t] = x[row=lo][k=kk*32+hi*8+t],
//   bfrag(kk,nb)[t] = W[k=kk*32+hi*8+t][e=nb*16+lo],
//   acc[nb][q] = Y[row=lo][e = nb*16 + hi*4 + q]
template <int NRG, int RSB, int JOFFB, bool CROSS>
__device__ __forceinline__ void pair_loop(
    const unsigned char* smem, const ushort8* __restrict__ W2,
    float* __restrict__ out, int fa, int fb_, int row0,
    int wv, int lo, int hi, int lane) {
  const int NP = CROSS ? 100 : 45;
  int prev_ii = -1;
  ushort8 af[NRG][2];

  int ii, jj;
  {
    int q = wv;
    if constexpr (CROSS) { ii = q / 10; jj = q - ii * 10; }
    else { int s = 0; ii = 0; while (s + 9 - ii <= q) { s += 9 - ii; ++ii; } jj = ii + 1 + (q - s); }
  }
  ushort8 wnx[8];
  {
    int gi = fa + ii, gj = fb_ + jj;
    size_t wb = (size_t)(gi * kF - ((gi * (gi + 1)) >> 1) + gj - gi - 1) * 512;
#pragma unroll
    for (int f = 0; f < 8; ++f) wnx[f] = W2[wb + f * 64 + lane];
  }

  for (int q = wv; q < NP; q += 8) {
    const int cii = ii, cjj = jj;
    ushort8 wc[8];
#pragma unroll
    for (int f = 0; f < 8; ++f) wc[f] = wnx[f];

    int qn = q + 8;
    if (qn < NP) {                       // prefetch next pair's W now
      if constexpr (CROSS) { ii = qn / 10; jj = qn - ii * 10; }
      else { int s = 0; ii = 0; while (s + 9 - ii <= qn) { s += 9 - ii; ++ii; } jj = ii + 1 + (qn - s); }
      int gi = fa + ii, gj = fb_ + jj;
      size_t wb = (size_t)(gi * kF - ((gi * (gi + 1)) >> 1) + gj - gi - 1) * 512;
#pragma unroll
      for (int f = 0; f < 8; ++f) wnx[f] = W2[wb + f * 64 + lane];
    }

    if (cii != prev_ii) {                // afrag cache for all row-groups
      prev_ii = cii;
#pragma unroll
      for (int rg = 0; rg < NRG; ++rg) {
        int row_l = rg * 16 + lo;
        int sw = (row_l & 7) << 4;
#pragma unroll
        for (int kk = 0; kk < 2; ++kk)
          af[rg][kk] = *(const ushort8*)(
              smem + row_l * RSB + ((cii * 128 + kk * 64 + hi * 16) ^ sw));
      }
    }

    const int gi = fa + cii, gj = fb_ + cjj;
    const int p = gi * kF - ((gi * (gi + 1)) >> 1) + gj - gi - 1;

#pragma unroll
    for (int rg = 0; rg < NRG; ++rg) {
      int row_l = rg * 16 + lo;
      int sw = (row_l & 7) << 4;
      u16x4 xj[4];
#pragma unroll
      for (int nb = 0; nb < 4; ++nb)
        xj[nb] = *(const u16x4*)(
            smem + row_l * RSB + ((JOFFB + cjj * 128 + nb * 32 + hi * 8) ^ sw));

      f32x4 acc[4];
#pragma unroll
      for (int nb = 0; nb < 4; ++nb) acc[nb] = f32x4{0.f, 0.f, 0.f, 0.f};
#pragma unroll
      for (int kk = 0; kk < 2; ++kk)
#pragma unroll
        for (int nb = 0; nb < 4; ++nb)
          acc[nb] = __builtin_amdgcn_mfma_f32_16x16x32_bf16(
              __builtin_bit_cast(bf16x8, wc[kk * 4 + nb]),
              __builtin_bit_cast(bf16x8, af[rg][kk]), acc[nb], 0, 0, 0);

      float sm[4];
#pragma unroll
      for (int nb = 0; nb < 4; ++nb)
        sm[nb] = fmaf(acc[nb][3], bf2f(xj[nb][3]),
                 fmaf(acc[nb][2], bf2f(xj[nb][2]),
                 fmaf(acc[nb][1], bf2f(xj[nb][1]),
                      acc[nb][0] * bf2f(xj[nb][0]))));
      float sum = (sm[0] + sm[1]) + (sm[2] + sm[3]);
      sum += __shfl_xor(sum, 16, 64);
      sum += __shfl_xor(sum, 32, 64);
      if (hi == 0) out[(size_t)(row0 + row_l) * kP + p] = sum;
    }
  }
}

// single cooperative kernel: phase1 packs W->W2 (each class packs its own
// slice -> XCD-local when gid&7 maps to XCD; correctness via device fence +
// grid sync regardless), phase2 stages x fp32->bf16 LDS and runs pair loop.
__global__ __launch_bounds__(512) void bilinear_coop(
    const float* __restrict__ x, const float* __restrict__ W,
    ushort8* __restrict__ W2, float* __restrict__ out) {
  __shared__ __align__(16) unsigned char smem[163840];
  const int gid = blockIdx.x;          // 0..255
  const int tid = threadIdx.x;
  const int lane = tid & 63;
  const int wv = tid >> 6;
  const int lo = lane & 15;
  const int hi = lane >> 4;
  const int item = ((gid & 7) << 5) + (gid >> 3);  // XCD-chunked

  // class decode (shared by both phases)
  int fa, fb_, row0, tile;
  bool cross;
  if (item < 192) {
    cross = true;
    int cls = item >> 5; tile = item & 31;
    int a, b;
    if (cls < 3)      { a = 0; b = cls + 1; }
    else if (cls < 5) { a = 1; b = cls - 1; }
    else              { a = 2; b = 3; }
    fa = a * 10; fb_ = b * 10; row0 = tile * 64;
  } else {
    cross = false;
    int d = (item - 192) >> 4; tile = (item - 192) & 15;
    fa = d * 10; fb_ = fa; row0 = tile * 128;
  }

  // ---- phase 1: pack this class's W slice into W2 via LDS transpose
  unsigned short* wl = (unsigned short*)smem;   // 8 KB staging
  const int NP   = cross ? 100 : 45;
  const int STEP = cross ? 32 : 16;
  for (int q = tile; q < NP; q += STEP) {
    int ii, jj;
    if (cross) { ii = q / 10; jj = q - ii * 10; }
    else { int s = 0; ii = 0; while (s + 9 - ii <= q) { s += 9 - ii; ++ii; } jj = ii + 1 + (q - s); }
    const int gi = fa + ii, gj = fb_ + jj;
    const int p = gi * kF - ((gi * (gi + 1)) >> 1) + gj - gi - 1;
    const float* wp = W + (size_t)p * (kD * kD);
#pragma unroll
    for (int k = 0; k < 2; ++k) {       // 1024 f32x4 over 512 threads
      int i4 = tid + (k << 9);
      f32x4 v = *(const f32x4*)(wp + i4 * 4);
      u16x4 o;
#pragma unroll
      for (int t = 0; t < 4; ++t) o[t] = f2bf_bits(v[t]);
      *(u16x4*)(wl + i4 * 4) = o;
    }
    __syncthreads();
    {
      int v = tid;                      // 512 dst vectors, one per thread
      int frag = v >> 6, ln = v & 63;
      int kk = frag >> 2, nb = frag & 3;
      int l2 = ln & 15, h2 = ln >> 4;
      ushort8 o;
#pragma unroll
      for (int t = 0; t < 8; ++t)
        o[t] = wl[(kk * 32 + h2 * 8 + t) * 64 + nb * 16 + l2];
      W2[(size_t)p * 512 + v] = o;
    }
    __syncthreads();
  }
  __threadfence();                      // device-scope release of W2
  cg::this_grid().sync();

  // ---- phase 2: stage x fp32 -> bf16 LDS (same layout as r8), pair loop
  if (cross) {
#pragma unroll
    for (int k = 0; k < 20; ++k) {
      int c = tid + (k << 9);
      int rowc = c / 160;
      int rem = c - rowc * 160;
      int half = rem >= 80;
      int off16 = half ? rem - 80 : rem;
      const float* src = x + (size_t)(row0 + rowc) * kFD
                         + (half ? fb_ : fa) * 64 + off16 * 8;
      f32x4 v0 = *(const f32x4*)src;
      f32x4 v1 = *(const f32x4*)(src + 4);
      ushort8 o;
#pragma unroll
      for (int t = 0; t < 4; ++t) { o[t] = f2bf_bits(v0[t]); o[t + 4] = f2bf_bits(v1[t]); }
      int dst = rowc * 2560 + ((half * 1280 + off16 * 16) ^ ((rowc & 7) << 4));
      *(ushort8*)(smem + dst) = o;
    }
    __syncthreads();
    pair_loop<4, 2560, 1280, true>(smem, W2, out, fa, fb_, row0, wv, lo, hi, lane);
  } else {
#pragma unroll
    for (int k = 0; k < 20; ++k) {
      int c = tid + (k << 9);
      int rowc = c / 80;
      int off16 = c - rowc * 80;
      const float* src = x + (size_t)(row0 + rowc) * kFD + fa * 64 + off16 * 8;
      f32x4 v0 = *(const f32x4*)src;
      f32x4 v1 = *(const f32x4*)(src + 4);
      ushort8 o;
#pragma unroll
      for (int t = 0; t < 4; ++t) { o[t] = f2bf_bits(v0[t]); o[t + 4] = f2bf_bits(v1[t]); }
      *(ushort8*)(smem + rowc * 1280 + ((off16 * 16) ^ ((rowc & 7) << 4))) = o;
    }
    __syncthreads();
    pair_loop<8, 1280, 0, false>(smem, W2, out, fa, fa, row0, wv, lo, hi, lane);
  }
}

// ---- fallback (no workspace): round-1 kernel ----
__global__ __launch_bounds__(256) void bilinear_fb(
    const float* __restrict__ x, const float* __restrict__ W,
    float* __restrict__ out) {
  const int gid = blockIdx.x;
  const int item = (gid & 7) * 390 + (gid >> 3);
  const int p = item >> 2;
  const int btile = item & 3;
  int i_f = 0, s = 0;
  while (s + (kF - 1 - i_f) <= p) { s += kF - 1 - i_f; ++i_f; }
  const int j_f = i_f + 1 + (p - s);
  const int lane = threadIdx.x & 63;
  const int wave = threadIdx.x >> 6;
  const int lo = lane & 15;
  const int hi = lane >> 4;
  const float* wp = W + (size_t)p * (kD * kD);
  bf16x8 bfrag[2][4];
#pragma unroll
  for (int kk = 0; kk < 2; ++kk)
#pragma unroll
    for (int nb = 0; nb < 4; ++nb) {
      ushort8 tmp;
#pragma unroll
      for (int t = 0; t < 8; ++t)
        tmp[t] = f2bf_bits(wp[(kk * 32 + hi * 8 + t) * kD + nb * 16 + lo]);
      bfrag[kk][nb] = __builtin_bit_cast(bf16x8, tmp);
    }
  const int b0 = btile * 512;
  for (int pass = 0; pass < 8; ++pass) {
    const int rb = b0 + pass * 64 + wave * 16;
    const float* xi = x + (size_t)(rb + lo) * kFD + i_f * kD;
    bf16x8 afrag[2];
#pragma unroll
    for (int kk = 0; kk < 2; ++kk) {
      f32x4 v0 = *(const f32x4*)(xi + kk * 32 + hi * 8);
      f32x4 v1 = *(const f32x4*)(xi + kk * 32 + hi * 8 + 4);
      ushort8 tmp;
#pragma unroll
      for (int t = 0; t < 4; ++t) {
        tmp[t] = f2bf_bits(v0[t]);
        tmp[t + 4] = f2bf_bits(v1[t]);
      }
      afrag[kk] = __builtin_bit_cast(bf16x8, tmp);
    }
    f32x4 acc[4];
#pragma unroll
    for (int nb = 0; nb < 4; ++nb) acc[nb] = f32x4{0.f, 0.f, 0.f, 0.f};
#pragma unroll
    for (int kk = 0; kk < 2; ++kk)
#pragma unroll
      for (int nb = 0; nb < 4; ++nb)
        acc[nb] = __builtin_amdgcn_mfma_f32_16x16x32_bf16(afrag[kk], bfrag[kk][nb],
                                                          acc[nb], 0, 0, 0);
#pragma unroll
    for (int q = 0; q < 4; ++q) {
      const int row = rb + hi * 4 + q;
      const float* xj = x + (size_t)row * kFD + j_f * kD + lo;
      float sum = 0.f;
#pragma unroll
      for (int nb = 0; nb < 4; ++nb) sum += acc[nb][q] * xj[nb * 16];
      sum += __shfl_xor(sum, 1, 64);
      sum += __shfl_xor(sum, 2, 64);
      sum += __shfl_xor(sum, 4, 64);
      sum += __shfl_xor(sum, 8, 64);
      if (lo == 0) out[(size_t)row * kP + p] = sum;
    }
  }
}

extern "C" void kernel_launch(void* const* d_in, const int* in_sizes, int n_in,
                              void* d_out, int out_size, void* d_ws, size_t ws_size,
                              hipStream_t stream) {
  const float* x = (const float*)d_in[0];
  const float* W = (const float*)d_in[1];
  float* out = (float*)d_out;
  if (ws_size >= WS_NEEDED) {
    ushort8* W2 = (ushort8*)d_ws;
    void* args[] = {(void*)&x, (void*)&W, (void*)&W2, (void*)&out};
    hipLaunchCooperativeKernel((void*)bilinear_coop, dim3(256), dim3(512),
                               args, 0, stream);
  } else {
    hipLaunchKernelGGL(bilinear_fb, dim3(3120), dim3(256), 0, stream, x, W, out);
  }
}

// Round 13
// 107.122 us; speedup vs baseline: 1.6451x; 1.6451x over previous
//
#include <hip/hip_runtime.h>
#include <hip/hip_bf16.h>

typedef float f32x4 __attribute__((ext_vector_type(4)));
typedef __bf16 bf16x8 __attribute__((ext_vector_type(8)));
typedef unsigned short ushort8 __attribute__((ext_vector_type(8)));
typedef unsigned short u16x4 __attribute__((ext_vector_type(4)));

constexpr int kB = 2048;
constexpr int kF = 40;
constexpr int kD = 64;
constexpr int kP = 780;            // 40*39/2
constexpr int kFD = kF * kD;       // 2560

constexpr size_t W2_BYTES  = (size_t)kP * 512 * 16;   // 6.39 MB packed W
constexpr size_t WS_NEEDED = W2_BYTES;

__device__ __forceinline__ unsigned short f2bf_bits(float f) {
  unsigned u = __builtin_bit_cast(unsigned, f);
  u += 0x7FFFu + ((u >> 16) & 1u);
  return (unsigned short)(u >> 16);
}
__device__ __forceinline__ float bf2f(unsigned short u) {
  return __builtin_bit_cast(float, (unsigned)u << 16);
}

// ---- prepass: W -> bf16 fragment-packed via LDS transpose (verified r8/r11)
// W2[p][frag=kk*4+nb][lane], value[t] = W[p][kk*32+hi*8+t][nb*16+lo]
__global__ __launch_bounds__(256) void w_pack(
    const float* __restrict__ W, ushort8* __restrict__ W2) {
  __shared__ unsigned short wl[4096];
  const int p = blockIdx.x;
  const int tid = threadIdx.x;
  const float* wp = W + (size_t)p * (kD * kD);
#pragma unroll
  for (int k = 0; k < 4; ++k) {
    int i4 = tid + (k << 8);
    f32x4 v = *(const f32x4*)(wp + i4 * 4);
    u16x4 o;
#pragma unroll
    for (int t = 0; t < 4; ++t) o[t] = f2bf_bits(v[t]);
    *(u16x4*)(wl + i4 * 4) = o;
  }
  __syncthreads();
#pragma unroll
  for (int r = 0; r < 2; ++r) {
    int v = tid + (r << 8);
    int frag = v >> 6, ln = v & 63;
    int kk = frag >> 2, nb = frag & 3;
    int lo = ln & 15, h2 = ln >> 4;
    ushort8 o;
#pragma unroll
    for (int t = 0; t < 8; ++t)
      o[t] = wl[(kk * 32 + h2 * 8 + t) * 64 + nb * 16 + lo];
    W2[(size_t)p * 512 + v] = o;
  }
}

// ---- main v5: 32 rows x ALL 40 fields in 160KB LDS, one template,
// contiguous pair chunks per wave (af reload only when i changes).
// MFMA mapping (verified r8): mfma(W_frag, X_frag) ->
//   acc[nb][q] = Y[row=lo][e = nb*16 + hi*4 + q]
__global__ __launch_bounds__(512, 2) void bilinear_main5(
    const float* __restrict__ x, const ushort8* __restrict__ W2,
    float* __restrict__ out) {
  __shared__ __align__(16) unsigned char smem[163840];
  const int gid = blockIdx.x;
  const int xcd = gid & 7;
  const int quarter = xcd >> 1;                  // W2 quarter pinned to XCD pair
  const int rt = ((gid >> 3) << 1) + (xcd & 1);  // row tile 0..63
  const int row0 = rt * 32;
  const int tid = threadIdx.x;
  const int lane = tid & 63;
  const int wv = tid >> 6;
  const int lo = lane & 15;
  const int hi = lane >> 4;

  // wave's contiguous pair chunk: quarter*195 + [wv*24+min(wv,3), +24/25)
  const int cnt = 24 + (wv < 3 ? 1 : 0);
  int p = quarter * 195 + wv * 24 + (wv < 3 ? wv : 3);
  int i = 0, s = 0;                   // decode (i,j) of first p
  while (s + (kF - 1 - i) <= p) { s += kF - 1 - i; ++i; }
  int j = i + 1 + (p - s);

  // issue first W2 prefetch BEFORE staging (hides cold-L2 latency)
  ushort8 wnx[8];
#pragma unroll
  for (int f = 0; f < 8; ++f) wnx[f] = W2[(size_t)p * 512 + f * 64 + lane];

  // stage 32 rows x 2560 cols fp32 -> bf16 LDS, XOR-swizzled
#pragma unroll
  for (int k = 0; k < 20; ++k) {
    int c = tid + (k << 9);           // 0..10239
    int row = c / 320;                // 320 16B-vecs per row
    int off = c - row * 320;
    const float* src = x + (size_t)(row0 + row) * kFD + off * 8;
    f32x4 v0 = *(const f32x4*)src;
    f32x4 v1 = *(const f32x4*)(src + 4);
    ushort8 o;
#pragma unroll
    for (int t = 0; t < 4; ++t) { o[t] = f2bf_bits(v0[t]); o[t + 4] = f2bf_bits(v1[t]); }
    *(ushort8*)(smem + row * 5120 + ((off * 16) ^ ((row & 7) << 4))) = o;
  }
  __syncthreads();

  int cur_i = -1;
  ushort8 af[2][2];

  for (int it = 0; it < cnt; ++it, ++p) {
    ushort8 wc[8];
#pragma unroll
    for (int f = 0; f < 8; ++f) wc[f] = wnx[f];
    if (it + 1 < cnt) {               // 1-deep prefetch, contiguous p+1
#pragma unroll
      for (int f = 0; f < 8; ++f)
        wnx[f] = W2[(size_t)(p + 1) * 512 + f * 64 + lane];
    }

    if (i != cur_i) {                 // af cache: reload only when i changes
      cur_i = i;
#pragma unroll
      for (int rg = 0; rg < 2; ++rg) {
        int row_l = rg * 16 + lo;
        int sw = (row_l & 7) << 4;
#pragma unroll
        for (int kk = 0; kk < 2; ++kk)
          af[rg][kk] = *(const ushort8*)(
              smem + row_l * 5120 + ((i * 128 + kk * 64 + hi * 16) ^ sw));
      }
    }

#pragma unroll
    for (int rg = 0; rg < 2; ++rg) {
      int row_l = rg * 16 + lo;
      int sw = (row_l & 7) << 4;
      u16x4 xj[4];
#pragma unroll
      for (int nb = 0; nb < 4; ++nb)
        xj[nb] = *(const u16x4*)(
            smem + row_l * 5120 + ((j * 128 + nb * 32 + hi * 8) ^ sw));

      f32x4 acc[4];
#pragma unroll
      for (int nb = 0; nb < 4; ++nb) acc[nb] = f32x4{0.f, 0.f, 0.f, 0.f};
#pragma unroll
      for (int kk = 0; kk < 2; ++kk)
#pragma unroll
        for (int nb = 0; nb < 4; ++nb)
          acc[nb] = __builtin_amdgcn_mfma_f32_16x16x32_bf16(
              __builtin_bit_cast(bf16x8, wc[kk * 4 + nb]),
              __builtin_bit_cast(bf16x8, af[rg][kk]), acc[nb], 0, 0, 0);

      float sm[4];
#pragma unroll
      for (int nb = 0; nb < 4; ++nb)
        sm[nb] = fmaf(acc[nb][3], bf2f(xj[nb][3]),
                 fmaf(acc[nb][2], bf2f(xj[nb][2]),
                 fmaf(acc[nb][1], bf2f(xj[nb][1]),
                      acc[nb][0] * bf2f(xj[nb][0]))));
      float sum = (sm[0] + sm[1]) + (sm[2] + sm[3]);
      sum += __shfl_xor(sum, 16, 64);
      sum += __shfl_xor(sum, 32, 64);
      if (hi == 0) out[(size_t)(row0 + row_l) * kP + p] = sum;
    }

    ++j;                              // advance (i,j) in lex order
    if (j == kF) { ++i; j = i + 1; }
  }
}

// ---- fallback (no workspace): round-1 kernel ----
__global__ __launch_bounds__(256) void bilinear_fb(
    const float* __restrict__ x, const float* __restrict__ W,
    float* __restrict__ out) {
  const int gid = blockIdx.x;
  const int item = (gid & 7) * 390 + (gid >> 3);
  const int p = item >> 2;
  const int btile = item & 3;
  int i_f = 0, s = 0;
  while (s + (kF - 1 - i_f) <= p) { s += kF - 1 - i_f; ++i_f; }
  const int j_f = i_f + 1 + (p - s);
  const int lane = threadIdx.x & 63;
  const int wave = threadIdx.x >> 6;
  const int lo = lane & 15;
  const int hi = lane >> 4;
  const float* wp = W + (size_t)p * (kD * kD);
  bf16x8 bfrag[2][4];
#pragma unroll
  for (int kk = 0; kk < 2; ++kk)
#pragma unroll
    for (int nb = 0; nb < 4; ++nb) {
      ushort8 tmp;
#pragma unroll
      for (int t = 0; t < 8; ++t)
        tmp[t] = f2bf_bits(wp[(kk * 32 + hi * 8 + t) * kD + nb * 16 + lo]);
      bfrag[kk][nb] = __builtin_bit_cast(bf16x8, tmp);
    }
  const int b0 = btile * 512;
  for (int pass = 0; pass < 8; ++pass) {
    const int rb = b0 + pass * 64 + wave * 16;
    const float* xi = x + (size_t)(rb + lo) * kFD + i_f * kD;
    bf16x8 afrag[2];
#pragma unroll
    for (int kk = 0; kk < 2; ++kk) {
      f32x4 v0 = *(const f32x4*)(xi + kk * 32 + hi * 8);
      f32x4 v1 = *(const f32x4*)(xi + kk * 32 + hi * 8 + 4);
      ushort8 tmp;
#pragma unroll
      for (int t = 0; t < 4; ++t) {
        tmp[t] = f2bf_bits(v0[t]);
        tmp[t + 4] = f2bf_bits(v1[t]);
      }
      afrag[kk] = __builtin_bit_cast(bf16x8, tmp);
    }
    f32x4 acc[4];
#pragma unroll
    for (int nb = 0; nb < 4; ++nb) acc[nb] = f32x4{0.f, 0.f, 0.f, 0.f};
#pragma unroll
    for (int kk = 0; kk < 2; ++kk)
#pragma unroll
      for (int nb = 0; nb < 4; ++nb)
        acc[nb] = __builtin_amdgcn_mfma_f32_16x16x32_bf16(afrag[kk], bfrag[kk][nb],
                                                          acc[nb], 0, 0, 0);
#pragma unroll
    for (int q = 0; q < 4; ++q) {
      const int row = rb + hi * 4 + q;
      const float* xj = x + (size_t)row * kFD + j_f * kD + lo;
      float sum = 0.f;
#pragma unroll
      for (int nb = 0; nb < 4; ++nb) sum += acc[nb][q] * xj[nb * 16];
      sum += __shfl_xor(sum, 1, 64);
      sum += __shfl_xor(sum, 2, 64);
      sum += __shfl_xor(sum, 4, 64);
      sum += __shfl_xor(sum, 8, 64);
      if (lo == 0) out[(size_t)row * kP + p] = sum;
    }
  }
}

extern "C" void kernel_launch(void* const* d_in, const int* in_sizes, int n_in,
                              void* d_out, int out_size, void* d_ws, size_t ws_size,
                              hipStream_t stream) {
  const float* x = (const float*)d_in[0];
  const float* W = (const float*)d_in[1];
  float* out = (float*)d_out;
  if (ws_size >= WS_NEEDED) {
    ushort8* W2 = (ushort8*)d_ws;
    hipLaunchKernelGGL(w_pack, dim3(kP), dim3(256), 0, stream, W, W2);
    hipLaunchKernelGGL(bilinear_main5, dim3(256), dim3(512), 0, stream,
                       x, W2, out);
  } else {
    hipLaunchKernelGGL(bilinear_fb, dim3(3120), dim3(256), 0, stream, x, W, out);
  }
}